// Round 1
// baseline (36074.136 us; speedup 1.0000x reference)
//
#include <hip/hip_runtime.h>
#include <cstdint>
#include <cstddef>

// GRU: B=64, T=1024, IN=512, H=1024.
// out = (B,T,H) fp32 followed by h_n (1,B,H) fp32 in d_out.
//
// Structure (round 1, launch-per-step):
//   setup: convert x/U/W to bf16 in ws, init h (fp32 + bf16 mirror)
//   per step t: k_step1 computes z (fp32) and rh = r*h (bf16) via MFMA
//               k_step2 computes h_tilde, gates, writes h and out[.,t,.]
//   tail: copy final h -> d_out tail (h_n)
// MFMA inputs bf16; accumulation, gating, state, additive terms fp32.

constexpr int Bb = 64;
constexpr int Tt = 1024;
constexpr int IN = 512;
constexpr int H  = 1024;

typedef float  f32x4  __attribute__((ext_vector_type(4)));
typedef __bf16 bf16x8 __attribute__((ext_vector_type(8)));

__global__ void k_cvt(const float* __restrict__ src, __bf16* __restrict__ dst, int n) {
    int i = blockIdx.x * blockDim.x + threadIdx.x;
    if (i < n) dst[i] = (__bf16)src[i];
}

__global__ void k_init_h(const float* __restrict__ h0, float* __restrict__ h_fp,
                         __bf16* __restrict__ h_bf, int n) {
    int i = blockIdx.x * blockDim.x + threadIdx.x;
    if (i < n) {
        float v = h0[i];
        h_fp[i] = v;
        h_bf[i] = (__bf16)v;
    }
}

__global__ void k_tail(const float* __restrict__ h_fp, float* __restrict__ dst, int n) {
    int i = blockIdx.x * blockDim.x + threadIdx.x;
    if (i < n) dst[i] = h_fp[i];
}

// Phase 1: pre = h @ [Uz;Ur]^T + x_t @ [Wz;Wr]^T + b.
// grid = 128 blocks x 64 threads. Block = one wave, tile = 64 rows x 16 cols.
// Columns [0,1024) -> z, [1024,2048) -> r.
__global__ __launch_bounds__(64) void k_step1(
    const __bf16* __restrict__ h_bf,   // (64,1024) bf16, k-contiguous
    const __bf16* __restrict__ xbf,    // (B,T,IN) bf16
    const __bf16* __restrict__ Ucat,   // (2048,1024) = [Uz;Ur]
    const __bf16* __restrict__ Wcat,   // (2048,512)  = [Wz;Wr]
    const float*  __restrict__ bz, const float* __restrict__ br,
    const float*  __restrict__ h_fp,   // (64,1024) fp32 (old h)
    float*        __restrict__ z_fp,   // (64,1024) fp32
    __bf16*       __restrict__ rh_bf,  // (64,1024) bf16
    int t)
{
    const int lane = threadIdx.x;
    const int ln   = lane & 15;
    const int quad = lane >> 4;
    const int j0   = blockIdx.x * 16;   // 0..2047

    f32x4 acc[4];
    #pragma unroll
    for (int mt = 0; mt < 4; ++mt) { acc[mt][0]=0.f; acc[mt][1]=0.f; acc[mt][2]=0.f; acc[mt][3]=0.f; }

    // K over hidden (h @ U^T)
    const __bf16* Brow  = Ucat + (size_t)(j0 + ln) * H + quad * 8;
    const __bf16* Arow0 = h_bf + (size_t)ln * H + quad * 8;
    #pragma unroll 4
    for (int k = 0; k < H; k += 32) {
        bf16x8 bfrag = *(const bf16x8*)(Brow + k);
        #pragma unroll
        for (int mt = 0; mt < 4; ++mt) {
            bf16x8 afrag = *(const bf16x8*)(Arow0 + (size_t)mt * 16 * H + k);
            acc[mt] = __builtin_amdgcn_mfma_f32_16x16x32_bf16(afrag, bfrag, acc[mt], 0, 0, 0);
        }
    }
    // K over input (x_t @ W^T); x row stride between batch rows is T*IN
    const __bf16* BrowW = Wcat + (size_t)(j0 + ln) * IN + quad * 8;
    const __bf16* Xrow0 = xbf + ((size_t)ln * Tt + t) * IN + quad * 8;
    #pragma unroll 4
    for (int k = 0; k < IN; k += 32) {
        bf16x8 bfrag = *(const bf16x8*)(BrowW + k);
        #pragma unroll
        for (int mt = 0; mt < 4; ++mt) {
            bf16x8 afrag = *(const bf16x8*)(Xrow0 + (size_t)mt * 16 * Tt * IN + k);
            acc[mt] = __builtin_amdgcn_mfma_f32_16x16x32_bf16(afrag, bfrag, acc[mt], 0, 0, 0);
        }
    }

    const bool is_z = (j0 < H);
    const int  col  = (is_z ? j0 : j0 - H) + ln;
    const float bias = is_z ? bz[col] : br[col];
    #pragma unroll
    for (int mt = 0; mt < 4; ++mt) {
        #pragma unroll
        for (int r = 0; r < 4; ++r) {
            const int b = mt * 16 + quad * 4 + r;   // C/D: col=lane&15, row=(lane>>4)*4+reg
            const float pre = acc[mt][r] + bias;
            const float g = 1.f / (1.f + __expf(-pre));
            const size_t off = (size_t)b * H + col;
            if (is_z) z_fp[off] = g;
            else      rh_bf[off] = (__bf16)(g * h_fp[off]);
        }
    }
}

// Phase 2: h_tilde = tanh(rh @ Uh^T + x_t @ Wh^T + bh); h = (1-z)h + z*h_tilde.
// grid = 64 blocks x 64 threads.
__global__ __launch_bounds__(64) void k_step2(
    const __bf16* __restrict__ rh_bf,  // (64,1024) bf16
    const __bf16* __restrict__ xbf,    // (B,T,IN) bf16
    const __bf16* __restrict__ Uhbf,   // (1024,1024)
    const __bf16* __restrict__ Whbf,   // (1024,512)
    const float*  __restrict__ bh,
    const float*  __restrict__ z_fp,   // (64,1024)
    float*        __restrict__ h_fp,   // (64,1024) in/out
    __bf16*       __restrict__ h_bf,   // (64,1024) out (for next step's MFMA)
    float*        __restrict__ out,    // (B,T,H) fp32 = d_out
    int t)
{
    const int lane = threadIdx.x;
    const int ln   = lane & 15;
    const int quad = lane >> 4;
    const int j0   = blockIdx.x * 16;   // 0..1023

    f32x4 acc[4];
    #pragma unroll
    for (int mt = 0; mt < 4; ++mt) { acc[mt][0]=0.f; acc[mt][1]=0.f; acc[mt][2]=0.f; acc[mt][3]=0.f; }

    const __bf16* Brow  = Uhbf + (size_t)(j0 + ln) * H + quad * 8;
    const __bf16* Arow0 = rh_bf + (size_t)ln * H + quad * 8;
    #pragma unroll 4
    for (int k = 0; k < H; k += 32) {
        bf16x8 bfrag = *(const bf16x8*)(Brow + k);
        #pragma unroll
        for (int mt = 0; mt < 4; ++mt) {
            bf16x8 afrag = *(const bf16x8*)(Arow0 + (size_t)mt * 16 * H + k);
            acc[mt] = __builtin_amdgcn_mfma_f32_16x16x32_bf16(afrag, bfrag, acc[mt], 0, 0, 0);
        }
    }
    const __bf16* BrowW = Whbf + (size_t)(j0 + ln) * IN + quad * 8;
    const __bf16* Xrow0 = xbf + ((size_t)ln * Tt + t) * IN + quad * 8;
    #pragma unroll 4
    for (int k = 0; k < IN; k += 32) {
        bf16x8 bfrag = *(const bf16x8*)(BrowW + k);
        #pragma unroll
        for (int mt = 0; mt < 4; ++mt) {
            bf16x8 afrag = *(const bf16x8*)(Xrow0 + (size_t)mt * 16 * Tt * IN + k);
            acc[mt] = __builtin_amdgcn_mfma_f32_16x16x32_bf16(afrag, bfrag, acc[mt], 0, 0, 0);
        }
    }

    const int col = j0 + ln;
    const float bias = bh[col];
    #pragma unroll
    for (int mt = 0; mt < 4; ++mt) {
        #pragma unroll
        for (int r = 0; r < 4; ++r) {
            const int b = mt * 16 + quad * 4 + r;
            const float pre = acc[mt][r] + bias;
            // tanh(pre) = 1 - 2/(exp(2*pre)+1); robust at +/-inf
            const float e = __expf(2.f * pre);
            const float ht = 1.f - 2.f / (e + 1.f);
            const size_t off = (size_t)b * H + col;
            const float z = z_fp[off];
            const float h = h_fp[off];
            const float hn = (1.f - z) * h + z * ht;
            h_fp[off] = hn;
            h_bf[off] = (__bf16)hn;
            out[((size_t)b * Tt + t) * H + col] = hn;
        }
    }
}

extern "C" void kernel_launch(void* const* d_in, const int* in_sizes, int n_in,
                              void* d_out, int out_size, void* d_ws, size_t ws_size,
                              hipStream_t stream) {
    const float* x  = (const float*)d_in[0];
    const float* h0 = (const float*)d_in[1];
    const float* Wz = (const float*)d_in[2];
    const float* bz = (const float*)d_in[3];
    const float* Uz = (const float*)d_in[4];
    const float* Wr = (const float*)d_in[5];
    const float* br = (const float*)d_in[6];
    const float* Ur = (const float*)d_in[7];
    const float* Wh = (const float*)d_in[8];
    const float* bh = (const float*)d_in[9];
    const float* Uh = (const float*)d_in[10];
    float* out = (float*)d_out;

    char* p = (char*)d_ws;
    __bf16* xbf  = (__bf16*)p;  p += (size_t)Bb * Tt * IN * 2;   // 67,108,864 B
    __bf16* Ucat = (__bf16*)p;  p += (size_t)2 * H * H * 2;      // [Uz;Ur]
    __bf16* Uhbf = (__bf16*)p;  p += (size_t)H * H * 2;
    __bf16* Wcat = (__bf16*)p;  p += (size_t)2 * H * IN * 2;     // [Wz;Wr]
    __bf16* Whbf = (__bf16*)p;  p += (size_t)H * IN * 2;
    float*  h_fp = (float*)p;   p += (size_t)Bb * H * 4;
    float*  z_fp = (float*)p;   p += (size_t)Bb * H * 4;
    __bf16* h_bf = (__bf16*)p;  p += (size_t)Bb * H * 2;
    __bf16* rh_bf= (__bf16*)p;  p += (size_t)Bb * H * 2;

    auto cvt = [&](const float* s, __bf16* d, int n) {
        k_cvt<<<(n + 255) / 256, 256, 0, stream>>>(s, d, n);
    };
    cvt(x,  xbf,  Bb * Tt * IN);
    cvt(Uz, Ucat, H * H);
    cvt(Ur, Ucat + (size_t)H * H, H * H);
    cvt(Uh, Uhbf, H * H);
    cvt(Wz, Wcat, H * IN);
    cvt(Wr, Wcat + (size_t)H * IN, H * IN);
    cvt(Wh, Whbf, H * IN);
    k_init_h<<<(Bb * H + 255) / 256, 256, 0, stream>>>(h0, h_fp, h_bf, Bb * H);

    for (int t = 0; t < Tt; ++t) {
        k_step1<<<128, 64, 0, stream>>>(h_bf, xbf, Ucat, Wcat, bz, br, h_fp, z_fp, rh_bf, t);
        k_step2<<<64, 64, 0, stream>>>(rh_bf, xbf, Uhbf, Whbf, bh, z_fp, h_fp, h_bf, out, t);
    }
    k_tail<<<(Bb * H + 255) / 256, 256, 0, stream>>>(h_fp, out + (size_t)Bb * Tt * H, Bb * H);
}

// Round 2
// 32019.113 us; speedup vs baseline: 1.1266x; 1.1266x over previous
//
#include <hip/hip_runtime.h>
#include <cstdint>
#include <cstddef>

// GRU B=64, T=1024, IN=512, H=1024 — persistent cooperative kernel.
// Phase A: [z|r] = sigmoid(h@[Uz;Ur]^T + x_t@[Wz;Wr]^T + b), rh = r*h
// Phase B: h~ = tanh(rh@Uh^T + x_t@Wh^T + bh); h = (1-z)h + z*h~
// 256 blocks x 256 thr; 2 grid barriers per step (agent-scope atomics).

constexpr int Bb = 64;
constexpr int Tt = 1024;
constexpr int IN = 512;
constexpr int H  = 1024;
constexpr int NBLK = 256;
constexpr int NTHR = 256;

typedef float  f32x4  __attribute__((ext_vector_type(4)));
typedef __bf16 bf16x8 __attribute__((ext_vector_type(8)));

__global__ void k_cvt(const float* __restrict__ src, __bf16* __restrict__ dst, int n) {
    int i = blockIdx.x * blockDim.x + threadIdx.x;
    if (i < n) dst[i] = (__bf16)src[i];
}

__global__ void k_init_h(const float* __restrict__ h0, float* __restrict__ h_fp,
                         __bf16* __restrict__ h_bf, int n) {
    int i = blockIdx.x * blockDim.x + threadIdx.x;
    if (i < n) {
        float v = h0[i];
        h_fp[i] = v;
        h_bf[i] = (__bf16)v;
    }
}

// Grid barrier: bar[0]=arrive counter, bar[32]=generation (separate cachelines).
// Agent scope => cross-XCD L2 writeback/invalidate handled by the atomics.
__device__ inline void gbar(unsigned* bar) {
    __syncthreads();
    if (threadIdx.x == 0) {
        unsigned* cnt = bar;
        unsigned* gen = bar + 32;
        unsigned g = __hip_atomic_load(gen, __ATOMIC_RELAXED, __HIP_MEMORY_SCOPE_AGENT);
        unsigned a = __hip_atomic_fetch_add(cnt, 1u, __ATOMIC_ACQ_REL, __HIP_MEMORY_SCOPE_AGENT);
        if (a == (unsigned)(NBLK - 1)) {
            __hip_atomic_store(cnt, 0u, __ATOMIC_RELAXED, __HIP_MEMORY_SCOPE_AGENT);
            __hip_atomic_store(gen, g + 1u, __ATOMIC_RELEASE, __HIP_MEMORY_SCOPE_AGENT);
        } else {
            while (__hip_atomic_load(gen, __ATOMIC_RELAXED, __HIP_MEMORY_SCOPE_AGENT) == g) {}
            (void)__hip_atomic_load(gen, __ATOMIC_ACQUIRE, __HIP_MEMORY_SCOPE_AGENT);
        }
    }
    __syncthreads();
}

__global__ __launch_bounds__(NTHR, 1) void k_gru(
    __bf16*       __restrict__ h_bf,   // (64,1024)
    float*        __restrict__ h_fp,   // (64,1024)
    float*        __restrict__ z_fp,   // (64,1024)
    __bf16*       __restrict__ rh_bf,  // (64,1024)
    const __bf16* __restrict__ xbf,    // (64,1024,512)
    const __bf16* __restrict__ Ucat,   // (2048,1024) [Uz;Ur]
    const __bf16* __restrict__ Uhbf,   // (1024,1024)
    const __bf16* __restrict__ Wcat,   // (2048,512)  [Wz;Wr]
    const __bf16* __restrict__ Whbf,   // (1024,512)
    const float*  __restrict__ bz, const float* __restrict__ br,
    const float*  __restrict__ bh,
    float*        __restrict__ out,    // (64,1024,1024) + h_n tail
    unsigned*     bar)
{
    const int b    = blockIdx.x;
    const int tid  = threadIdx.x;
    const int lane = tid & 63;
    const int wave = tid >> 6;            // 0..3, splits K
    const int ln   = lane & 15;
    const int quad = lane >> 4;

    __shared__ float red[4 * 512];        // 8 KB split-K partials

    // Phase A tile: 128 col-tiles x 2 row-halves
    const int jA   = b >> 1;
    const int rowA = (b & 1) * 32;
    const int colA = jA * 16;
    // Phase B tile: 64 col-tiles x 4 row-quarters
    const int jB   = b >> 2;
    const int rowB = (b & 3) * 16;
    const int colB = jB * 16;

    // K chunk for this wave: logical kk in [s, s+384); kk<1024 -> U/h part,
    // else x/W part with kx = kk-1024.
    const int s  = wave * 384;
    const int eK = s + 384;
    const int uEnd = eK < 1024 ? eK : 1024;     // end of U part
    const int wBeg = s > 1024 ? s - 1024 : 0;   // start of W part (physical)
    const int wEnd = eK - 1024;                 // end of W part (physical)

    // t-invariant fragment base pointers
    const __bf16* BA  = Ucat + (size_t)(colA + ln) * H + quad * 8;
    const __bf16* A0  = h_bf + (size_t)(rowA + ln) * H + quad * 8;
    const __bf16* A1  = h_bf + (size_t)(rowA + 16 + ln) * H + quad * 8;
    const __bf16* BAW = Wcat + (size_t)(colA + ln) * IN + quad * 8;

    const __bf16* BB  = Uhbf + (size_t)(colB + ln) * H + quad * 8;
    const __bf16* R0  = rh_bf + (size_t)(rowB + ln) * H + quad * 8;
    const __bf16* BBW = Whbf + (size_t)(colB + ln) * IN + quad * 8;

    for (int t = 0; t < Tt; ++t) {
        // ---------------- Phase A ----------------
        {
            f32x4 acc0 = {0.f, 0.f, 0.f, 0.f};
            f32x4 acc1 = {0.f, 0.f, 0.f, 0.f};
            #pragma unroll 4
            for (int kk = s; kk < uEnd; kk += 32) {
                bf16x8 bf = *(const bf16x8*)(BA + kk);
                acc0 = __builtin_amdgcn_mfma_f32_16x16x32_bf16(*(const bf16x8*)(A0 + kk), bf, acc0, 0, 0, 0);
                acc1 = __builtin_amdgcn_mfma_f32_16x16x32_bf16(*(const bf16x8*)(A1 + kk), bf, acc1, 0, 0, 0);
            }
            const __bf16* X0 = xbf + ((size_t)(rowA + ln) * Tt + t) * IN + quad * 8;
            const __bf16* X1 = xbf + ((size_t)(rowA + 16 + ln) * Tt + t) * IN + quad * 8;
            #pragma unroll 4
            for (int kx = wBeg; kx < wEnd; kx += 32) {
                bf16x8 bf = *(const bf16x8*)(BAW + kx);
                acc0 = __builtin_amdgcn_mfma_f32_16x16x32_bf16(*(const bf16x8*)(X0 + kx), bf, acc0, 0, 0, 0);
                acc1 = __builtin_amdgcn_mfma_f32_16x16x32_bf16(*(const bf16x8*)(X1 + kx), bf, acc1, 0, 0, 0);
            }
            float* my = red + wave * 512;
            #pragma unroll
            for (int r = 0; r < 4; ++r) {
                my[(quad * 4 + r) * 16 + ln]        = acc0[r];
                my[(16 + quad * 4 + r) * 16 + ln]   = acc1[r];
            }
            __syncthreads();
            #pragma unroll
            for (int e2 = tid; e2 < 512; e2 += NTHR) {
                float sm = red[e2] + red[512 + e2] + red[1024 + e2] + red[1536 + e2];
                const int rl = e2 >> 4, cl = e2 & 15;
                const int row = rowA + rl;
                const int c   = colA + cl;
                if (c < H) {
                    z_fp[(size_t)row * H + c] = 1.f / (1.f + __expf(-(sm + bz[c])));
                } else {
                    const int cc = c - H;
                    const float rv = 1.f / (1.f + __expf(-(sm + br[cc])));
                    const size_t off = (size_t)row * H + cc;
                    rh_bf[off] = (__bf16)(rv * h_fp[off]);
                }
            }
        }
        gbar(bar);
        // ---------------- Phase B ----------------
        {
            f32x4 acc = {0.f, 0.f, 0.f, 0.f};
            #pragma unroll 4
            for (int kk = s; kk < uEnd; kk += 32) {
                bf16x8 bf = *(const bf16x8*)(BB + kk);
                acc = __builtin_amdgcn_mfma_f32_16x16x32_bf16(*(const bf16x8*)(R0 + kk), bf, acc, 0, 0, 0);
            }
            const __bf16* X0 = xbf + ((size_t)(rowB + ln) * Tt + t) * IN + quad * 8;
            #pragma unroll 4
            for (int kx = wBeg; kx < wEnd; kx += 32) {
                bf16x8 bf = *(const bf16x8*)(BBW + kx);
                acc = __builtin_amdgcn_mfma_f32_16x16x32_bf16(*(const bf16x8*)(X0 + kx), bf, acc, 0, 0, 0);
            }
            float* my = red + wave * 256;
            #pragma unroll
            for (int r = 0; r < 4; ++r) my[(quad * 4 + r) * 16 + ln] = acc[r];
            __syncthreads();
            {
                const int e2 = tid;
                float sm = red[e2] + red[256 + e2] + red[512 + e2] + red[768 + e2];
                const int rl = e2 >> 4, cl = e2 & 15;
                const int row = rowB + rl;
                const int c   = colB + cl;
                const float pre = sm + bh[c];
                const float ex = __expf(2.f * pre);
                const float ht = 1.f - 2.f / (ex + 1.f);
                const size_t off = (size_t)row * H + c;
                const float zv = z_fp[off];
                const float hv = h_fp[off];
                const float hn = (1.f - zv) * hv + zv * ht;
                h_fp[off] = hn;
                h_bf[off] = (__bf16)hn;
                out[((size_t)row * Tt + t) * H + c] = hn;
            }
        }
        gbar(bar);
    }

    // tail: h_n = final h
    const int gid = b * NTHR + tid;
    if (gid < Bb * H) out[(size_t)Bb * Tt * H + gid] = h_fp[gid];
}

extern "C" void kernel_launch(void* const* d_in, const int* in_sizes, int n_in,
                              void* d_out, int out_size, void* d_ws, size_t ws_size,
                              hipStream_t stream) {
    const float* x  = (const float*)d_in[0];
    const float* h0 = (const float*)d_in[1];
    const float* Wz = (const float*)d_in[2];
    const float* bz = (const float*)d_in[3];
    const float* Uz = (const float*)d_in[4];
    const float* Wr = (const float*)d_in[5];
    const float* br = (const float*)d_in[6];
    const float* Ur = (const float*)d_in[7];
    const float* Wh = (const float*)d_in[8];
    const float* bh = (const float*)d_in[9];
    const float* Uh = (const float*)d_in[10];
    float* out = (float*)d_out;

    char* p = (char*)d_ws;
    __bf16* xbf  = (__bf16*)p;  p += (size_t)Bb * Tt * IN * 2;
    __bf16* Ucat = (__bf16*)p;  p += (size_t)2 * H * H * 2;
    __bf16* Uhbf = (__bf16*)p;  p += (size_t)H * H * 2;
    __bf16* Wcat = (__bf16*)p;  p += (size_t)2 * H * IN * 2;
    __bf16* Whbf = (__bf16*)p;  p += (size_t)H * IN * 2;
    float*  h_fp = (float*)p;   p += (size_t)Bb * H * 4;
    float*  z_fp = (float*)p;   p += (size_t)Bb * H * 4;
    __bf16* h_bf = (__bf16*)p;  p += (size_t)Bb * H * 2;
    __bf16* rh_bf= (__bf16*)p;  p += (size_t)Bb * H * 2;
    unsigned* bar= (unsigned*)p; p += 256;

    auto cvt = [&](const float* s, __bf16* d, int n) {
        k_cvt<<<(n + 255) / 256, 256, 0, stream>>>(s, d, n);
    };
    cvt(x,  xbf,  Bb * Tt * IN);
    cvt(Uz, Ucat, H * H);
    cvt(Ur, Ucat + (size_t)H * H, H * H);
    cvt(Uh, Uhbf, H * H);
    cvt(Wz, Wcat, H * IN);
    cvt(Wr, Wcat + (size_t)H * IN, H * IN);
    cvt(Wh, Whbf, H * IN);
    k_init_h<<<(Bb * H + 255) / 256, 256, 0, stream>>>(h0, h_fp, h_bf, Bb * H);
    hipMemsetAsync(bar, 0, 256, stream);

    void* args[] = {
        (void*)&h_bf, (void*)&h_fp, (void*)&z_fp, (void*)&rh_bf, (void*)&xbf,
        (void*)&Ucat, (void*)&Uhbf, (void*)&Wcat, (void*)&Whbf,
        (void*)&bz, (void*)&br, (void*)&bh, (void*)&out, (void*)&bar
    };
    hipLaunchCooperativeKernel((const void*)k_gru, dim3(NBLK), dim3(NTHR),
                               args, 0, stream);
}